// Round 10
// baseline (140.430 us; speedup 1.0000x reference)
//
#include <hip/hip_runtime.h>
#include <hip/hip_bf16.h>
#include <stdint.h>

typedef __attribute__((ext_vector_type(8))) short short8;
typedef __attribute__((ext_vector_type(4))) float f32x4;

#define N_HEADS 12
#define HD      64
#define BSZ     8
#define TSZ     1024
#define CSZ     768
#define MSZ     (BSZ * TSZ)   /* 8192 */
#define N3      (3 * CSZ)     /* 2304 */
#define LDA     72            /* padded LDS stride for attn S-tile */

static __device__ __forceinline__ unsigned short f2bf(float f) {
    union { float f; uint32_t u; } v; v.f = f;
    uint32_t r = v.u + 0x7fffu + ((v.u >> 16) & 1u);
    return (unsigned short)(r >> 16);
}

// async global->LDS, 16B per lane, LDS dest = wave-uniform base + lane*16
static __device__ __forceinline__ void gload16(const unsigned short* g,
                                               unsigned short* l) {
    __builtin_amdgcn_global_load_lds(
        (const __attribute__((address_space(1))) void*)g,
        (__attribute__((address_space(3))) void*)l, 16, 0, 0);
}

// ---------------- fp32 -> bf16 conversion ----------------
__global__ void cvt_f32_to_bf16(const float* __restrict__ s,
                                unsigned short* __restrict__ d, int n) {
    int i = (blockIdx.x * blockDim.x + threadIdx.x) * 4;
    if (i + 3 < n) {
        float4 f = *reinterpret_cast<const float4*>(s + i);
        ushort4 u;
        u.x = f2bf(f.x); u.y = f2bf(f.y); u.z = f2bf(f.z); u.w = f2bf(f.w);
        *reinterpret_cast<ushort4*>(d + i) = u;
    }
}

// ---------------- QKV projection GEMM (r5 structure + XCD swizzle) --------
// bf16 gload_lds staging into linear LDS [128][64]; 2 barriers per K-step.
// 1D grid 1152; xcd = bid&7 owns bm in [xcd*8, xcd*8+8) x all 18 bn,
// bm-minor: W-block (196KB) resident across 8 bms, x-slice (1.6MB) resident
// for the whole XCD pass -> cuts the ~5x tile re-fetch seen at 70MB.
__global__ __launch_bounds__(256, 2) void qkv_gemm(
    const unsigned short* __restrict__ xb,   // [8192][768] bf16
    const unsigned short* __restrict__ wb,   // [2304][768] bf16
    const float* __restrict__ bias,          // [2304] f32
    unsigned short* __restrict__ qo,
    unsigned short* __restrict__ ko,
    unsigned short* __restrict__ vto)
{
    __shared__ unsigned short At[128 * 64];
    __shared__ unsigned short Bt[128 * 64];
    const int tid = threadIdx.x;
    const int lane = tid & 63;
    const int w = tid >> 6;
    const int lr = lane >> 4, lc = lane & 15;
    const int xcd = blockIdx.x & 7, idx = blockIdx.x >> 3;   // idx 0..143
    const int bm = xcd * 8 + (idx & 7);     // 0..63
    const int bn = idx >> 3;                // 0..17
    const int m0 = bm * 128;
    const int n0 = bn * 128;
    const int wm = (w >> 1) * 64, wn = (w & 1) * 64;

    const unsigned short* ga = xb + (size_t)(m0 + w * 32 + (lane >> 3)) * CSZ + (lane & 7) * 8;
    const unsigned short* gb = wb + (size_t)(n0 + w * 32 + (lane >> 3)) * CSZ + (lane & 7) * 8;
    unsigned short* la = At + (w * 32) * 64;
    unsigned short* lb = Bt + (w * 32) * 64;

    f32x4 acc[4][4] = {};

    for (int kt = 0; kt < CSZ; kt += 64) {
        __syncthreads();
        #pragma unroll
        for (int j = 0; j < 4; ++j) {
            gload16(ga + (size_t)j * 8 * CSZ + kt, la + j * 8 * 64);
            gload16(gb + (size_t)j * 8 * CSZ + kt, lb + j * 8 * 64);
        }
        __syncthreads();
        #pragma unroll
        for (int ks = 0; ks < 2; ++ks) {
            short8 af[4], bf[4];
            #pragma unroll
            for (int mi = 0; mi < 4; ++mi)
                af[mi] = *reinterpret_cast<const short8*>(
                    At + (wm + mi * 16 + lc) * 64 + ks * 32 + lr * 8);
            #pragma unroll
            for (int ni = 0; ni < 4; ++ni)
                bf[ni] = *reinterpret_cast<const short8*>(
                    Bt + (wn + ni * 16 + lc) * 64 + ks * 32 + lr * 8);
            #pragma unroll
            for (int mi = 0; mi < 4; ++mi)
                #pragma unroll
                for (int ni = 0; ni < 4; ++ni)
                    acc[mi][ni] = __builtin_amdgcn_mfma_f32_16x16x32_bf16(
                        af[mi], bf[ni], acc[mi][ni], 0, 0, 0);
        }
    }

    const int sec = n0 / CSZ;
    const int nb = n0 - sec * CSZ;
    #pragma unroll
    for (int ni = 0; ni < 4; ++ni) {
        int ncol = wn + ni * 16 + lc;
        int nn = nb + ncol;
        float badd = bias[n0 + ncol];
        int h = nn >> 6, d = nn & 63;
        #pragma unroll
        for (int mi = 0; mi < 4; ++mi) {
            #pragma unroll
            for (int r = 0; r < 4; ++r) {
                int m = m0 + wm + mi * 16 + lr * 4 + r;
                int bb = m >> 10, t = m & 1023;
                int plane = bb * N_HEADS + h;
                float v = acc[mi][ni][r] + badd;
                if (sec == 0)
                    qo[((size_t)plane * TSZ + t) * HD + d] = f2bf(v * 0.125f);
                else if (sec == 1)
                    ko[((size_t)plane * TSZ + t) * HD + d] = f2bf(v);
                else
                    vto[((size_t)plane * HD + d) * TSZ + t] = f2bf(v);
            }
        }
    }
}

// ---------------- causal-ReLU attention (K reg-dbuf + V early-issue) ------
// 1536 blocks; xcd = bid&7 owns 12 heads (L2-local K/V). 2 waves/block,
// q-tiles (qt, 31-qt): every block = exactly 17 kv-steps. Per step:
// issue V loads -> QK(K_cur) -> prefetch K_next (crosses the loop back-edge,
// which the compiler won't pipeline itself) -> repack -> PV. The dependency-
// counted vmcnt keeps K_next in flight through repack+PV.
__global__ __launch_bounds__(128, 3) void attn_kernel(
    const unsigned short* __restrict__ q,    // [96][1024][64] bf16 (pre-scaled)
    const unsigned short* __restrict__ k,    // [96][1024][64] bf16
    const unsigned short* __restrict__ vt,   // [96][64][1024] bf16
    float* __restrict__ out)                 // [8][1024][768] f32
{
    __shared__ unsigned short smem[2 * 32 * LDA];
    const int wid = threadIdx.x >> 6;
    const int lane = threadIdx.x & 63;
    const int lr = lane >> 4, lc = lane & 15;
    const int xcd = blockIdx.x & 7, slot = blockIdx.x >> 3;
    const int bh = xcd * 12 + (slot >> 4);
    const int qt = slot & 15;
    const int qw = wid == 0 ? qt : 31 - qt;
    const int b = bh / N_HEADS, h = bh - b * N_HEADS;
    const size_t base = (size_t)bh * (TSZ * HD);
    const size_t vbase = (size_t)bh * (HD * TSZ);
    const int qrow0 = qw * 32;
    const int lastkt = qw >> 1;
    unsigned short* sm = smem + wid * 32 * LDA;

    short8 aq[2][2];
    #pragma unroll
    for (int ks = 0; ks < 2; ++ks)
        #pragma unroll
        for (int qi = 0; qi < 2; ++qi)
            aq[ks][qi] = *reinterpret_cast<const short8*>(
                q + base + (size_t)(qrow0 + qi * 16 + lc) * HD + ks * 32 + lr * 8);

    f32x4 y[2][4] = {};

#define LOADK(DST, KT)                                                      \
    do {                                                                    \
        _Pragma("unroll")                                                   \
        for (int ks = 0; ks < 2; ++ks)                                      \
            _Pragma("unroll")                                               \
            for (int ki = 0; ki < 4; ++ki)                                  \
                DST[ks * 4 + ki] = *reinterpret_cast<const short8*>(        \
                    k + base + (size_t)((KT) * 64 + ki * 16 + lc) * HD +    \
                    ks * 32 + lr * 8);                                      \
    } while (0)

#define STEPBODY(KT, KC, KN, DO_PRE)                                        \
    do {                                                                    \
        const int kv0 = (KT) * 64;                                          \
        short8 bv[8];                                                       \
        _Pragma("unroll")                                                   \
        for (int ks = 0; ks < 2; ++ks)                                      \
            _Pragma("unroll")                                               \
            for (int di = 0; di < 4; ++di)                                  \
                bv[ks * 4 + di] = *reinterpret_cast<const short8*>(         \
                    vt + vbase + (size_t)(di * 16 + lc) * TSZ + kv0 +       \
                    ks * 32 + lr * 8);                                      \
        f32x4 st[4][2] = {};                                                \
        _Pragma("unroll")                                                   \
        for (int ks = 0; ks < 2; ++ks)                                      \
            _Pragma("unroll")                                               \
            for (int ki = 0; ki < 4; ++ki)                                  \
                _Pragma("unroll")                                           \
                for (int qi = 0; qi < 2; ++qi)                              \
                    st[ki][qi] = __builtin_amdgcn_mfma_f32_16x16x32_bf16(   \
                        KC[ks * 4 + ki], aq[ks][qi], st[ki][qi], 0, 0, 0);  \
        if (DO_PRE) LOADK(KN, (KT) + 1);                                    \
        const bool diag = ((KT) == lastkt);                                 \
        _Pragma("unroll")                                                   \
        for (int ki = 0; ki < 4; ++ki) {                                    \
            _Pragma("unroll")                                               \
            for (int qi = 0; qi < 2; ++qi) {                                \
                float vv[4];                                                \
                _Pragma("unroll")                                           \
                for (int r = 0; r < 4; ++r) {                               \
                    float s = fmaxf(st[ki][qi][r], 0.0f);                   \
                    if (diag && (kv0 + ki * 16 + lr * 4 + r >               \
                                 qrow0 + qi * 16 + lc))                     \
                        s = 0.0f;                                           \
                    vv[r] = s;                                              \
                }                                                           \
                __hip_bfloat162 p0 = __float22bfloat162_rn(make_float2(vv[0], vv[1])); \
                __hip_bfloat162 p1 = __float22bfloat162_rn(make_float2(vv[2], vv[3])); \
                uint2 pk;                                                   \
                pk.x = *reinterpret_cast<unsigned*>(&p0);                   \
                pk.y = *reinterpret_cast<unsigned*>(&p1);                   \
                *reinterpret_cast<uint2*>(                                  \
                    sm + (qi * 16 + lc) * LDA + ki * 16 + lr * 4) = pk;     \
            }                                                               \
        }                                                                   \
        _Pragma("unroll")                                                   \
        for (int ks = 0; ks < 2; ++ks) {                                    \
            short8 as[2];                                                   \
            _Pragma("unroll")                                               \
            for (int qi = 0; qi < 2; ++qi)                                  \
                as[qi] = *reinterpret_cast<const short8*>(                  \
                    sm + (qi * 16 + lc) * LDA + ks * 32 + lr * 8);          \
            _Pragma("unroll")                                               \
            for (int qi = 0; qi < 2; ++qi)                                  \
                _Pragma("unroll")                                           \
                for (int di = 0; di < 4; ++di)                              \
                    y[qi][di] = __builtin_amdgcn_mfma_f32_16x16x32_bf16(    \
                        as[qi], bv[ks * 4 + di], y[qi][di], 0, 0, 0);       \
        }                                                                   \
    } while (0)

    short8 kA[8], kB[8];
    LOADK(kA, 0);
    for (int kt = 0; kt <= lastkt; kt += 2) {
        const bool p1 = (kt + 1 <= lastkt);
        STEPBODY(kt, kA, kB, p1);
        if (p1) STEPBODY(kt + 1, kB, kA, (kt + 2 <= lastkt));
    }
#undef LOADK
#undef STEPBODY

    #pragma unroll
    for (int qi = 0; qi < 2; ++qi)
        #pragma unroll
        for (int di = 0; di < 4; ++di)
            #pragma unroll
            for (int r = 0; r < 4; ++r) {
                int t = qrow0 + qi * 16 + lr * 4 + r;
                int d = di * 16 + lc;
                out[((size_t)b * TSZ + t) * CSZ + h * HD + d] = y[qi][di][r];
            }
}

extern "C" void kernel_launch(void* const* d_in, const int* in_sizes, int n_in,
                              void* d_out, int out_size, void* d_ws, size_t ws_size,
                              hipStream_t stream) {
    const float* x    = (const float*)d_in[0];
    const float* W    = (const float*)d_in[1];
    const float* bias = (const float*)d_in[2];
    float* out = (float*)d_out;

    unsigned short* xb  = (unsigned short*)d_ws;                 // 8192*768
    unsigned short* wb  = xb + (size_t)MSZ * CSZ;                // 2304*768
    unsigned short* qo  = wb + (size_t)N3 * CSZ;                 // 96*1024*64
    unsigned short* ko  = qo + (size_t)MSZ * CSZ;
    unsigned short* vto = ko + (size_t)MSZ * CSZ;

    const int nx = MSZ * CSZ;   // 6291456
    const int nw = N3 * CSZ;    // 1769472
    cvt_f32_to_bf16<<<nx / 1024, 256, 0, stream>>>(x, xb, nx);
    cvt_f32_to_bf16<<<nw / 1024, 256, 0, stream>>>(W, wb, nw);
    qkv_gemm<<<dim3(1152), 256, 0, stream>>>(xb, wb, bias, qo, ko, vto);
    attn_kernel<<<dim3(1536), 128, 0, stream>>>(qo, ko, vto, out);
}

// Round 11
// 103.228 us; speedup vs baseline: 1.3604x; 1.3604x over previous
//
#include <hip/hip_runtime.h>
#include <hip/hip_bf16.h>
#include <stdint.h>

typedef __attribute__((ext_vector_type(8))) short short8;
typedef __attribute__((ext_vector_type(4))) float f32x4;

#define N_HEADS 12
#define HD      64
#define BSZ     8
#define TSZ     1024
#define CSZ     768
#define MSZ     (BSZ * TSZ)   /* 8192 */
#define N3      (3 * CSZ)     /* 2304 */

static __device__ __forceinline__ unsigned short f2bf(float f) {
    union { float f; uint32_t u; } v; v.f = f;
    uint32_t r = v.u + 0x7fffu + ((v.u >> 16) & 1u);
    return (unsigned short)(r >> 16);
}

// async global->LDS, 16B per lane, LDS dest = wave-uniform base + lane*16
static __device__ __forceinline__ void gload16(const unsigned short* g,
                                               unsigned short* l) {
    __builtin_amdgcn_global_load_lds(
        (const __attribute__((address_space(1))) void*)g,
        (__attribute__((address_space(3))) void*)l, 16, 0, 0);
}

// ---------------- fp32 -> bf16 conversion ----------------
__global__ void cvt_f32_to_bf16(const float* __restrict__ s,
                                unsigned short* __restrict__ d, int n) {
    int i = (blockIdx.x * blockDim.x + threadIdx.x) * 4;
    if (i + 3 < n) {
        float4 f = *reinterpret_cast<const float4*>(s + i);
        ushort4 u;
        u.x = f2bf(f.x); u.y = f2bf(f.y); u.z = f2bf(f.z); u.w = f2bf(f.w);
        *reinterpret_cast<ushort4*>(d + i) = u;
    }
}

// ---------------- QKV projection GEMM (r10: kept, XCD-swizzled) -----------
__global__ __launch_bounds__(256, 2) void qkv_gemm(
    const unsigned short* __restrict__ xb,   // [8192][768] bf16
    const unsigned short* __restrict__ wb,   // [2304][768] bf16
    const float* __restrict__ bias,          // [2304] f32
    unsigned short* __restrict__ qo,
    unsigned short* __restrict__ ko,
    unsigned short* __restrict__ vto)
{
    __shared__ unsigned short At[128 * 64];
    __shared__ unsigned short Bt[128 * 64];
    const int tid = threadIdx.x;
    const int lane = tid & 63;
    const int w = tid >> 6;
    const int lr = lane >> 4, lc = lane & 15;
    const int xcd = blockIdx.x & 7, idx = blockIdx.x >> 3;   // idx 0..143
    const int bm = xcd * 8 + (idx & 7);     // 0..63
    const int bn = idx >> 3;                // 0..17
    const int m0 = bm * 128;
    const int n0 = bn * 128;
    const int wm = (w >> 1) * 64, wn = (w & 1) * 64;

    const unsigned short* ga = xb + (size_t)(m0 + w * 32 + (lane >> 3)) * CSZ + (lane & 7) * 8;
    const unsigned short* gb = wb + (size_t)(n0 + w * 32 + (lane >> 3)) * CSZ + (lane & 7) * 8;
    unsigned short* la = At + (w * 32) * 64;
    unsigned short* lb = Bt + (w * 32) * 64;

    f32x4 acc[4][4] = {};

    for (int kt = 0; kt < CSZ; kt += 64) {
        __syncthreads();
        #pragma unroll
        for (int j = 0; j < 4; ++j) {
            gload16(ga + (size_t)j * 8 * CSZ + kt, la + j * 8 * 64);
            gload16(gb + (size_t)j * 8 * CSZ + kt, lb + j * 8 * 64);
        }
        __syncthreads();
        #pragma unroll
        for (int ks = 0; ks < 2; ++ks) {
            short8 af[4], bf[4];
            #pragma unroll
            for (int mi = 0; mi < 4; ++mi)
                af[mi] = *reinterpret_cast<const short8*>(
                    At + (wm + mi * 16 + lc) * 64 + ks * 32 + lr * 8);
            #pragma unroll
            for (int ni = 0; ni < 4; ++ni)
                bf[ni] = *reinterpret_cast<const short8*>(
                    Bt + (wn + ni * 16 + lc) * 64 + ks * 32 + lr * 8);
            #pragma unroll
            for (int mi = 0; mi < 4; ++mi)
                #pragma unroll
                for (int ni = 0; ni < 4; ++ni)
                    acc[mi][ni] = __builtin_amdgcn_mfma_f32_16x16x32_bf16(
                        af[mi], bf[ni], acc[mi][ni], 0, 0, 0);
        }
    }

    const int sec = n0 / CSZ;
    const int nb = n0 - sec * CSZ;
    #pragma unroll
    for (int ni = 0; ni < 4; ++ni) {
        int ncol = wn + ni * 16 + lc;
        int nn = nb + ncol;
        float badd = bias[n0 + ncol];
        int h = nn >> 6, d = nn & 63;
        #pragma unroll
        for (int mi = 0; mi < 4; ++mi) {
            #pragma unroll
            for (int r = 0; r < 4; ++r) {
                int m = m0 + wm + mi * 16 + lr * 4 + r;
                int bb = m >> 10, t = m & 1023;
                int plane = bb * N_HEADS + h;
                float v = acc[mi][ni][r] + badd;
                if (sec == 0)
                    qo[((size_t)plane * TSZ + t) * HD + d] = f2bf(v * 0.125f);
                else if (sec == 1)
                    ko[((size_t)plane * TSZ + t) * HD + d] = f2bf(v);
                else
                    vto[((size_t)plane * HD + d) * TSZ + t] = f2bf(v);
            }
        }
    }
}

// ---------------- causal-ReLU attention (shared-LDS K/V, 2-phase) ---------
// Block = 2 waves = one 64-row q-tile of one head; wave wid owns rows
// [j*64+wid*32, +32). Both waves run j+1 kv-steps (uniform -> barrier-safe).
// Per step: STAGE(kt+1) via gload_lds (source pre-swizzled, LDS linear)
// issued BEFORE compute(kt) so the end-of-step __syncthreads drain only pays
// leftover latency. K/V/S LDS reads use the r7-verified XOR involution
// (chunk ^= row&7) -> conflict-free. LDS 40KB -> 4 blocks/CU.
__global__ __launch_bounds__(128, 2) void attn_kernel(
    const unsigned short* __restrict__ q,    // [96][1024][64] bf16 (pre-scaled)
    const unsigned short* __restrict__ k,    // [96][1024][64] bf16
    const unsigned short* __restrict__ vt,   // [96][64][1024] bf16
    float* __restrict__ out)                 // [8][1024][768] f32
{
    __shared__ unsigned short Kl[2][64 * 64];
    __shared__ unsigned short Vl[2][64 * 64];
    __shared__ unsigned short Sl[2][32 * 64];
    const int tid = threadIdx.x;
    const int wid = tid >> 6;
    const int lane = tid & 63;
    const int lr = lane >> 4, lc = lane & 15;
    const int xcd = blockIdx.x & 7, slot = blockIdx.x >> 3;
    const int bh = xcd * 12 + (slot >> 4);   // 12 heads per XCD (L2-local)
    const int j = slot & 15;                 // q 64-tile index
    const int b = bh / N_HEADS, h = bh - b * N_HEADS;
    const size_t base = (size_t)bh * (TSZ * HD);
    const size_t vbase = (size_t)bh * (HD * TSZ);
    const int qrow0 = j * 64 + wid * 32;
    unsigned short* sm = Sl[wid];
    const int nt = j + 1;

    // Q fragments (MFMA B operand for the S^T trick)
    short8 aq[2][2];
    #pragma unroll
    for (int ks = 0; ks < 2; ++ks)
        #pragma unroll
        for (int qi = 0; qi < 2; ++qi)
            aq[ks][qi] = *reinterpret_cast<const short8*>(
                q + base + (size_t)(qrow0 + qi * 16 + lc) * HD + ks * 32 + lr * 8);

    f32x4 y[2][4] = {};

    // stage K,V tile KT into buffer BI: 512 chunks each; chunk c: row c>>3,
    // source col-chunk (c&7)^(row&7) -> LDS linear dest (involution).
#define STAGEKV(KT, BI)                                                     \
    do {                                                                    \
        _Pragma("unroll")                                                   \
        for (int i = 0; i < 4; ++i) {                                       \
            int c = i * 128 + tid;                                          \
            int r_ = c >> 3;                                                \
            int c8 = (c & 7) ^ (r_ & 7);                                    \
            gload16(k + base + (size_t)((KT) * 64 + r_) * HD + c8 * 8,      \
                    Kl[BI] + c * 8);                                        \
            gload16(vt + vbase + (size_t)r_ * TSZ + (KT) * 64 + c8 * 8,     \
                    Vl[BI] + c * 8);                                        \
        }                                                                   \
    } while (0)

    STAGEKV(0, 0);
    __syncthreads();

    for (int kt = 0; kt < nt; ++kt) {
        const int bi = kt & 1;
        if (kt + 1 < nt) STAGEKV(kt + 1, bi ^ 1);   // prefetch over compute
        const unsigned short* Kb = Kl[bi];
        const unsigned short* Vb = Vl[bi];
        // ---- QK: S^T frags (rows kv 4x16, cols q 2x16) ----
        f32x4 st[4][2] = {};
        #pragma unroll
        for (int ks = 0; ks < 2; ++ks) {
            short8 ak[4];
            #pragma unroll
            for (int ki = 0; ki < 4; ++ki)
                ak[ki] = *reinterpret_cast<const short8*>(
                    Kb + (ki * 16 + lc) * 64 + (((ks * 4 + lr) ^ (lc & 7)) * 8));
            #pragma unroll
            for (int ki = 0; ki < 4; ++ki)
                #pragma unroll
                for (int qi = 0; qi < 2; ++qi)
                    st[ki][qi] = __builtin_amdgcn_mfma_f32_16x16x32_bf16(
                        ak[ki], aq[ks][qi], st[ki][qi], 0, 0, 0);
        }
        // ---- mask + ReLU + bf16 repack into swizzled S tile ----
        const bool diag = (kt == j);
        const int kv0 = kt * 64;
        #pragma unroll
        for (int ki = 0; ki < 4; ++ki) {
            #pragma unroll
            for (int qi = 0; qi < 2; ++qi) {
                float vv[4];
                #pragma unroll
                for (int r = 0; r < 4; ++r) {
                    float s = fmaxf(st[ki][qi][r], 0.0f);
                    if (diag && (kv0 + ki * 16 + lr * 4 + r > qrow0 + qi * 16 + lc))
                        s = 0.0f;
                    vv[r] = s;
                }
                __hip_bfloat162 p0 = __float22bfloat162_rn(make_float2(vv[0], vv[1]));
                __hip_bfloat162 p1 = __float22bfloat162_rn(make_float2(vv[2], vv[3]));
                uint2 pk;
                pk.x = *reinterpret_cast<unsigned*>(&p0);
                pk.y = *reinterpret_cast<unsigned*>(&p1);
                int row = qi * 16 + lc;
                int chunk = (2 * ki + (lr >> 1)) ^ (row & 7);
                *reinterpret_cast<uint2*>(
                    sm + row * 64 + chunk * 8 + (lr & 1) * 4) = pk;
            }
        }
        // ---- PV: y[q][d] += S[q][kv] * V^T[d][kv] ----
        #pragma unroll
        for (int ks = 0; ks < 2; ++ks) {
            short8 as[2], bv[4];
            #pragma unroll
            for (int qi = 0; qi < 2; ++qi)
                as[qi] = *reinterpret_cast<const short8*>(
                    sm + (qi * 16 + lc) * 64 + (((ks * 4 + lr) ^ (lc & 7)) * 8));
            #pragma unroll
            for (int di = 0; di < 4; ++di)
                bv[di] = *reinterpret_cast<const short8*>(
                    Vb + (di * 16 + lc) * 64 + (((ks * 4 + lr) ^ (lc & 7)) * 8));
            #pragma unroll
            for (int qi = 0; qi < 2; ++qi)
                #pragma unroll
                for (int di = 0; di < 4; ++di)
                    y[qi][di] = __builtin_amdgcn_mfma_f32_16x16x32_bf16(
                        as[qi], bv[di], y[qi][di], 0, 0, 0);
        }
        __syncthreads();   // drains this step's prefetch + WAR protection
    }
#undef STAGEKV

    #pragma unroll
    for (int qi = 0; qi < 2; ++qi)
        #pragma unroll
        for (int di = 0; di < 4; ++di)
            #pragma unroll
            for (int r = 0; r < 4; ++r) {
                int t = qrow0 + qi * 16 + lr * 4 + r;
                int d = di * 16 + lc;
                out[((size_t)b * TSZ + t) * CSZ + h * HD + d] = y[qi][di][r];
            }
}

extern "C" void kernel_launch(void* const* d_in, const int* in_sizes, int n_in,
                              void* d_out, int out_size, void* d_ws, size_t ws_size,
                              hipStream_t stream) {
    const float* x    = (const float*)d_in[0];
    const float* W    = (const float*)d_in[1];
    const float* bias = (const float*)d_in[2];
    float* out = (float*)d_out;

    unsigned short* xb  = (unsigned short*)d_ws;                 // 8192*768
    unsigned short* wb  = xb + (size_t)MSZ * CSZ;                // 2304*768
    unsigned short* qo  = wb + (size_t)N3 * CSZ;                 // 96*1024*64
    unsigned short* ko  = qo + (size_t)MSZ * CSZ;
    unsigned short* vto = ko + (size_t)MSZ * CSZ;

    const int nx = MSZ * CSZ;   // 6291456
    const int nw = N3 * CSZ;    // 1769472
    cvt_f32_to_bf16<<<nx / 1024, 256, 0, stream>>>(x, xb, nx);
    cvt_f32_to_bf16<<<nw / 1024, 256, 0, stream>>>(W, wb, nw);
    qkv_gemm<<<dim3(1152), 256, 0, stream>>>(xb, wb, bias, qo, ko, vto);
    attn_kernel<<<dim3(1536), 128, 0, stream>>>(qo, ko, vto, out);
}